// Round 11
// baseline (68.120 us; speedup 1.0000x reference)
//
#include <hip/hip_runtime.h>
#include <math.h>

namespace {
constexpr int B = 4, N = 4, C = 64, H = 128, W = 256, L = 5;
constexpr int HW = H * W;
constexpr int WAVES = 8;          // waves per block
constexpr int CPW = C / WAVES;    // channels per wave = 8
}

// 16-byte quad load with only 4-byte alignment guarantee.
typedef float f4v __attribute__((ext_vector_type(4), aligned(4)));

__global__ __launch_bounds__(512, 4) void atten_comm_kernel(
    const float* __restrict__ x,    // (B*N, C, H, W)
    const float* __restrict__ P,    // (B, L, L, 4, 4)
    float* __restrict__ out)        // (B, C, H, W)
{
    __shared__ float sred[WAVES][N][64];

    const int b    = blockIdx.z;
    const int h    = blockIdx.y;
    const int lane = (int)(threadIdx.x & 63);
    const int wv   = (int)(threadIdx.x >> 6);
    const int w    = (blockIdx.x << 6) + lane;

    // normalized grid coords (align_corners=True)
    const float gx = -1.0f + (2.0f / (float)(W - 1)) * (float)w;
    const float gy = -1.0f + (2.0f / (float)(H - 1)) * (float)h;

    const float* basep[N];
    int   voff0[N], voff1[N];   // element offsets of the two row-quads
    float ux4[N][4];            // x-weights scattered into the 4-word window
    float wyv0[N], wyv1[N];     // y weights (validity folded)

#pragma unroll
    for (int n = 0; n < N; ++n) {
        // P[b, 0, n, r, c]; strides: b:L*L*16, i:L*16, j:16, r:4, c:1
        const float* p = P + ((size_t)b * L * L + (size_t)n) * 16;
        const float a  = p[0];
        const float bb = p[1] * ((float)H / (float)W);
        const float cc = p[3] * (2.0f / (4.0f * 0.4f * (float)W));
        const float d  = p[4] * ((float)W / (float)H);
        const float e  = p[5];
        const float ff = p[7] * (2.0f / (4.0f * 0.4f * (float)H));

        const float g0 = a * gx + bb * gy + cc;
        const float g1 = d * gx + e * gy + ff;
        const float ix = (g0 + 1.0f) * (0.5f * (float)(W - 1));
        const float iy = (g1 + 1.0f) * (0.5f * (float)(H - 1));

        const float fx0 = floorf(ix);
        const float fy0 = floorf(iy);
        const int x0 = (int)fx0, y0 = (int)fy0;
        const int y1 = y0 + 1;
        const float wx = ix - fx0;
        const float wy = iy - fy0;

        // quad window [xq, xq+3] always inside the row; both clamped x-taps
        // land inside it:
        const int xq  = min(max(x0, 0), W - 4);
        const int xc0 = min(max(x0, 0), W - 1);
        const int xc1 = min(max(x0 + 1, 0), W - 1);
        const int rel0 = xc0 - xq;      // in [0,3]
        const int rel1 = xc1 - xq;      // in [0,3]
        const float wx0v = (1.0f - wx) * ((x0 >= 0 && x0 < W) ? 1.0f : 0.0f);
        const float wx1v = wx * ((x0 + 1 >= 0 && x0 + 1 < W) ? 1.0f : 0.0f);
#pragma unroll
        for (int j = 0; j < 4; ++j) {
            ux4[n][j] = ((j == rel0) ? wx0v : 0.0f)
                      + ((j == rel1) ? wx1v : 0.0f);
        }

        const int yc0 = min(max(y0, 0), H - 1);
        const int yc1 = min(max(y1, 0), H - 1);
        wyv0[n] = (1.0f - wy) * ((y0 >= 0 && y0 < H) ? 1.0f : 0.0f);
        wyv1[n] = wy * ((y1 >= 0 && y1 < H) ? 1.0f : 0.0f);

        voff0[n] = yc0 * W + xq;
        voff1[n] = yc1 * W + xq;

        basep[n] = x + ((size_t)(b * N + n) * C + (size_t)(wv * CPW)) * HW;
    }

    // ---- gather: 8 quad-loads per channel issued before the FMAs ----
    float f[N][CPW];
#pragma unroll
    for (int cc = 0; cc < CPW; ++cc) {
        f4v q0[N], q1[N];
#pragma unroll
        for (int n = 0; n < N; ++n) {
            const float* pl = basep[n] + (size_t)cc * HW;
            q0[n] = *(const f4v*)(pl + voff0[n]);
            q1[n] = *(const f4v*)(pl + voff1[n]);
        }
#pragma unroll
        for (int n = 0; n < N; ++n) {
            const float d0 = ux4[n][0] * q0[n].x + ux4[n][1] * q0[n].y
                           + ux4[n][2] * q0[n].z + ux4[n][3] * q0[n].w;
            const float d1 = ux4[n][0] * q1[n].x + ux4[n][1] * q1[n].y
                           + ux4[n][2] * q1[n].z + ux4[n][3] * q1[n].w;
            f[n][cc] = wyv0[n] * d0 + wyv1[n] * d1;
        }
    }

    // ---- partial scores over this wave's channels ----
    float s[N] = {0.f, 0.f, 0.f, 0.f};
#pragma unroll
    for (int cc = 0; cc < CPW; ++cc) {
        const float q = f[0][cc];
#pragma unroll
        for (int n = 0; n < N; ++n) s[n] += q * f[n][cc];
    }

    // ---- cross-wave reduction via LDS (lane-stride-1, conflict-free) ----
#pragma unroll
    for (int n = 0; n < N; ++n) sred[wv][n][lane] = s[n];
    __syncthreads();

    float st[N];
#pragma unroll
    for (int n = 0; n < N; ++n) {
        float acc = 0.f;
#pragma unroll
        for (int v = 0; v < WAVES; ++v) acc += sred[v][n][lane];
        st[n] = acc;
    }

    const float scale = 0.125f;  // 1/sqrt(64)
    const float s0 = st[0] * scale, s1 = st[1] * scale;
    const float s2 = st[2] * scale, s3 = st[3] * scale;
    const float m  = fmaxf(fmaxf(s0, s1), fmaxf(s2, s3));
    const float e0 = expf(s0 - m);
    const float e1 = expf(s1 - m);
    const float e2 = expf(s2 - m);
    const float e3 = expf(s3 - m);
    const float inv = 1.0f / (e0 + e1 + e2 + e3);
    const float attn[N] = {e0 * inv, e1 * inv, e2 * inv, e3 * inv};

    // ---- context from registers + coalesced store ----
    float* op = out + ((size_t)b * C + (size_t)(wv * CPW)) * HW
                    + (size_t)h * W + (size_t)w;
#pragma unroll
    for (int cc = 0; cc < CPW; ++cc) {
        float ctx = 0.f;
#pragma unroll
        for (int n = 0; n < N; ++n) ctx += attn[n] * f[n][cc];
        op[(size_t)cc * HW] = ctx;
    }
}

extern "C" void kernel_launch(void* const* d_in, const int* in_sizes, int n_in,
                              void* d_out, int out_size, void* d_ws, size_t ws_size,
                              hipStream_t stream) {
    const float* x  = (const float*)d_in[0];
    const float* P  = (const float*)d_in[1];
    float* out = (float*)d_out;

    dim3 block(512, 1, 1);
    dim3 grid(W / 64, H, B);  // (4, 128, 4) = 2048 blocks, 16384 waves
    hipLaunchKernelGGL(atten_comm_kernel, grid, block, 0, stream, x, P, out);
}

// Round 12
// 45.654 us; speedup vs baseline: 1.4921x; 1.4921x over previous
//
#include <hip/hip_runtime.h>
#include <math.h>

namespace {
constexpr int B = 4, N = 4, C = 64, H = 128, W = 256, L = 5;
constexpr int HW = H * W;
constexpr int WAVES = 8;          // waves per block
constexpr int CPW = C / WAVES;    // channels per wave = 8
constexpr int NXCD = 8;
constexpr int NWG = B * (W / 64) * H;   // 2048, divisible by 8
}

// 8-byte pair load with only 4-byte alignment guarantee (x-taps are adjacent).
typedef float f2v __attribute__((ext_vector_type(2), aligned(4)));

__global__ __launch_bounds__(512, 4) void atten_comm_kernel(
    const float* __restrict__ x,    // (B*N, C, H, W)
    const float* __restrict__ P,    // (B, L, L, 4, 4)
    float* __restrict__ out)        // (B, C, H, W)
{
    __shared__ float sred[WAVES][N][64];

    // XCD-aware swizzle (T1): dispatch round-robins wg->XCD by (g % 8).
    // Give each XCD a contiguous orig-id chunk so consecutive-h blocks
    // (which share warped source rows) co-reside in one XCD's L2.
    const int g    = (int)blockIdx.x;
    const int orig = (g & (NXCD - 1)) * (NWG / NXCD) + (g >> 3);
    const int h    = orig & (H - 1);          // h fastest
    const int wc   = (orig >> 7) & 3;         // then w-chunk
    const int b    = orig >> 9;               // then batch

    const int lane = (int)(threadIdx.x & 63);
    const int wv   = (int)(threadIdx.x >> 6);
    const int w    = (wc << 6) + lane;

    // normalized grid coords (align_corners=True)
    const float gx = -1.0f + (2.0f / (float)(W - 1)) * (float)w;
    const float gy = -1.0f + (2.0f / (float)(H - 1)) * (float)h;

    const float* basep[N];
    int   voff0[N], voff1[N];               // element offsets of the two row pairs
    float u0x[N], u0y[N], u1x[N], u1y[N];   // folded bilinear+boundary weights

#pragma unroll
    for (int n = 0; n < N; ++n) {
        // P[b, 0, n, r, c]; strides: b:L*L*16, i:L*16, j:16, r:4, c:1
        const float* p = P + ((size_t)b * L * L + (size_t)n) * 16;
        const float a  = p[0];
        const float bb = p[1] * ((float)H / (float)W);
        const float cc = p[3] * (2.0f / (4.0f * 0.4f * (float)W));
        const float d  = p[4] * ((float)W / (float)H);
        const float e  = p[5];
        const float ff = p[7] * (2.0f / (4.0f * 0.4f * (float)H));

        const float g0 = a * gx + bb * gy + cc;
        const float g1 = d * gx + e * gy + ff;
        const float ix = (g0 + 1.0f) * (0.5f * (float)(W - 1));
        const float iy = (g1 + 1.0f) * (0.5f * (float)(H - 1));

        const float fx0 = floorf(ix);
        const float fy0 = floorf(iy);
        const int x0 = (int)fx0, y0 = (int)fy0;
        const int y1 = y0 + 1;
        const float wx = ix - fx0;
        const float wy = iy - fy0;

        // x-pair: load (xa, xa+1); both x-taps live in this window with
        // boundary cases folded into (ux, uy):
        const int   xa   = min(max(x0, 0), W - 2);
        const float wx0v = (1.0f - wx) * ((x0 >= 0 && x0 < W) ? 1.0f : 0.0f);
        const float wx1v = wx * ((x0 + 1 >= 0 && x0 + 1 < W) ? 1.0f : 0.0f);
        // interior: (wx0v, wx1v); x0==-1: taps shift left -> (wx1v, 0);
        // x0==W-1: taps shift right -> (0, wx0v); fully OOB collapses to 0.
        const float ux = (x0 < 0) ? wx1v : ((x0 > W - 2) ? 0.0f : wx0v);
        const float uy = (x0 < 0) ? 0.0f : ((x0 > W - 2) ? wx0v : wx1v);

        const int yc0 = min(max(y0, 0), H - 1);
        const int yc1 = min(max(y1, 0), H - 1);
        const float wyv0 = (1.0f - wy) * ((y0 >= 0 && y0 < H) ? 1.0f : 0.0f);
        const float wyv1 = wy * ((y1 >= 0 && y1 < H) ? 1.0f : 0.0f);

        u0x[n] = ux * wyv0;  u0y[n] = uy * wyv0;
        u1x[n] = ux * wyv1;  u1y[n] = uy * wyv1;
        voff0[n] = yc0 * W + xa;
        voff1[n] = yc1 * W + xa;

        basep[n] = x + ((size_t)(b * N + n) * C + (size_t)(wv * CPW)) * HW;
    }

    // ---- gather: 8 pair-loads per channel issued before the FMAs ----
    float f[N][CPW];
#pragma unroll
    for (int cc = 0; cc < CPW; ++cc) {
        f2v t0[N], t1[N];
#pragma unroll
        for (int n = 0; n < N; ++n) {
            const float* pl = basep[n] + (size_t)cc * HW;
            t0[n] = *(const f2v*)(pl + voff0[n]);
            t1[n] = *(const f2v*)(pl + voff1[n]);
        }
#pragma unroll
        for (int n = 0; n < N; ++n) {
            f[n][cc] = u0x[n] * t0[n].x + u0y[n] * t0[n].y
                     + u1x[n] * t1[n].x + u1y[n] * t1[n].y;
        }
    }

    // ---- partial scores over this wave's channels ----
    float s[N] = {0.f, 0.f, 0.f, 0.f};
#pragma unroll
    for (int cc = 0; cc < CPW; ++cc) {
        const float q = f[0][cc];
#pragma unroll
        for (int n = 0; n < N; ++n) s[n] += q * f[n][cc];
    }

    // ---- cross-wave reduction via LDS (lane-stride-1, conflict-free) ----
#pragma unroll
    for (int n = 0; n < N; ++n) sred[wv][n][lane] = s[n];
    __syncthreads();

    float st[N];
#pragma unroll
    for (int n = 0; n < N; ++n) {
        float acc = 0.f;
#pragma unroll
        for (int v = 0; v < WAVES; ++v) acc += sred[v][n][lane];
        st[n] = acc;
    }

    const float scale = 0.125f;  // 1/sqrt(64)
    const float s0 = st[0] * scale, s1 = st[1] * scale;
    const float s2 = st[2] * scale, s3 = st[3] * scale;
    const float m  = fmaxf(fmaxf(s0, s1), fmaxf(s2, s3));
    const float e0 = expf(s0 - m);
    const float e1 = expf(s1 - m);
    const float e2 = expf(s2 - m);
    const float e3 = expf(s3 - m);
    const float inv = 1.0f / (e0 + e1 + e2 + e3);
    const float attn[N] = {e0 * inv, e1 * inv, e2 * inv, e3 * inv};

    // ---- context from registers + coalesced store ----
    float* op = out + ((size_t)b * C + (size_t)(wv * CPW)) * HW
                    + (size_t)h * W + (size_t)w;
#pragma unroll
    for (int cc = 0; cc < CPW; ++cc) {
        float ctx = 0.f;
#pragma unroll
        for (int n = 0; n < N; ++n) ctx += attn[n] * f[n][cc];
        op[(size_t)cc * HW] = ctx;
    }
}

extern "C" void kernel_launch(void* const* d_in, const int* in_sizes, int n_in,
                              void* d_out, int out_size, void* d_ws, size_t ws_size,
                              hipStream_t stream) {
    const float* x  = (const float*)d_in[0];
    const float* P  = (const float*)d_in[1];
    float* out = (float*)d_out;

    dim3 block(512, 1, 1);
    dim3 grid(NWG, 1, 1);  // 2048 blocks, 1D, XCD-swizzled in-kernel
    hipLaunchKernelGGL(atten_comm_kernel, grid, block, 0, stream, x, P, out);
}